// Round 2
// baseline (407.350 us; speedup 1.0000x reference)
//
#include <hip/hip_runtime.h>

// Conv1d: x (32, 64, 16384) f32, w (64, 64, 3) f32, bias (64) f32
// -> out (32, 64, 16382) f32, VALID, stride 1.
// GEMM view: out[co][n] = sum_kappa A[co][kappa] * B[kappa][n] + bias[co]
//   kappa = kk*64 + ci (kk-major). B[kappa][n] = x[ci][n+kk].
// One dwordx4 per (ci, col) feeds kk=0,1,2 of the same lane (contiguous in x).
// R2 fixes vs R1:
//  - NO indexed v[8] array: fragments built from 4 named x4 loads at a time.
//    Keeps total regs ~55 VGPR + 64 AGPR < the 128/wave cap from
//    __launch_bounds__(256,4) -> no scratch spills (R1: +318 MB HBM writes).
//  - Epilogue transposes the 64x256 out-tile through LDS (two 32KB passes,
//    union'd with the weight buffer) and flushes with coalesced dwordx4
//    row stores instead of 64 scalar misaligned dword stores per thread.

typedef __bf16 bf16x8 __attribute__((ext_vector_type(8)));
typedef float f32x16 __attribute__((ext_vector_type(16)));
typedef float f32x4u __attribute__((ext_vector_type(4), aligned(4)));   // 4B-aligned vec ld/st
typedef float f32x4a __attribute__((ext_vector_type(4), aligned(16)));  // LDS-aligned

#define C_IN 64
#define C_OUT 64
#define L_IN 16384
#define L_OUT 16382
#define NT 256          // n-columns per block
#define PW 200          // wl row pitch (elems); keeps 16B align, no conflicts

__device__ __forceinline__ unsigned short f2bf(float f) {
  unsigned u = __builtin_bit_cast(unsigned, f);
  return (unsigned short)((u + 0x7FFFu + ((u >> 16) & 1u)) >> 16);  // RNE
}

__global__ __launch_bounds__(256, 4) void conv1d_mfma(
    const float* __restrict__ x, const float* __restrict__ w,
    const float* __restrict__ bias, float* __restrict__ out) {
  // union: weight tile (25600 B) during main loop, out-tile buf (32x256 f32 =
  // 32768 B) during epilogue. 33 KB total -> still 4 blocks/CU.
  __shared__ __align__(16) unsigned char smem[32 * NT * 4];
  __shared__ float bias_s[C_OUT];
  unsigned short* wl = (unsigned short*)smem;
  float (*buf)[NT] = (float (*)[NT])smem;

  const int t = threadIdx.x;
  const int bx = blockIdx.x;
  const int b = bx >> 6;        // batch
  const int tile = bx & 63;     // l-tile
  const int l0 = tile * NT;

  // ---- weights -> LDS bf16, layout wl[co][kk*64 + ci] (kappa-order)
  for (int i = t; i < C_OUT * 192; i += 256) {
    int co = i / 192;
    int r = i - co * 192;
    int ci = r / 3;
    int kk = r - ci * 3;
    wl[co * PW + kk * 64 + ci] = f2bf(w[i]);
  }
  if (t < C_OUT) bias_s[t] = bias[t];
  __syncthreads();

  // ---- MFMA main loop: wave wv owns n in [wv*64, wv*64+64), all 64 co
  const int lane = t & 63;
  const int wv = t >> 6;
  const int half = lane >> 5;   // k-half within fragment
  const int ln = lane & 31;
  const int kh = half * 8;
  const int l_a = l0 + wv * 64 + ln;   // column for c=0 fragments

  const float* xb = x + (size_t)b * (C_IN * L_IN);

  f32x16 acc00 = {}, acc01 = {}, acc10 = {}, acc11 = {};

  if (!(tile == 63 && wv == 3)) {
    // ---- FAST PATH: dwordx4 per (ci, col) gives kk=0,1,2 in-lane.
    // Max touched col here = l_a+32+3 <= 16322 < 16384: no clamps needed.
#pragma unroll
    for (int g = 0; g < 4; ++g) {
      const int ci0 = g * 16 + kh;
      const float* pbase = xb + (size_t)ci0 * L_IN + l_a;
#pragma unroll
      for (int c = 0; c < 2; ++c) {
        const float* pc = pbase + c * 32;
        bf16x8 bf0, bf1, bf2;
#pragma unroll
        for (int jh = 0; jh < 2; ++jh) {   // 4 named loads at a time: no array,
          const float* pj = pc + (size_t)(jh * 4) * L_IN;  // no scratch spill
          f32x4u v0 = *(const f32x4u*)(pj);
          f32x4u v1 = *(const f32x4u*)(pj + L_IN);
          f32x4u v2 = *(const f32x4u*)(pj + 2 * L_IN);
          f32x4u v3 = *(const f32x4u*)(pj + 3 * L_IN);
          int j0 = jh * 4;
          bf0[j0 + 0] = (__bf16)v0[0]; bf1[j0 + 0] = (__bf16)v0[1]; bf2[j0 + 0] = (__bf16)v0[2];
          bf0[j0 + 1] = (__bf16)v1[0]; bf1[j0 + 1] = (__bf16)v1[1]; bf2[j0 + 1] = (__bf16)v1[2];
          bf0[j0 + 2] = (__bf16)v2[0]; bf1[j0 + 2] = (__bf16)v2[1]; bf2[j0 + 2] = (__bf16)v2[2];
          bf0[j0 + 3] = (__bf16)v3[0]; bf1[j0 + 3] = (__bf16)v3[1]; bf2[j0 + 3] = (__bf16)v3[2];
        }
#pragma unroll
        for (int kk = 0; kk < 3; ++kk) {
          bf16x8 a0 = *(const bf16x8*)&wl[ln * PW + kk * 64 + g * 16 + kh];
          bf16x8 a1 = *(const bf16x8*)&wl[(32 + ln) * PW + kk * 64 + g * 16 + kh];
          bf16x8 bb = (kk == 0) ? bf0 : ((kk == 1) ? bf1 : bf2);
          if (c == 0) {
            acc00 = __builtin_amdgcn_mfma_f32_32x32x16_bf16(a0, bb, acc00, 0, 0, 0);
            acc10 = __builtin_amdgcn_mfma_f32_32x32x16_bf16(a1, bb, acc10, 0, 0, 0);
          } else {
            acc01 = __builtin_amdgcn_mfma_f32_32x32x16_bf16(a0, bb, acc01, 0, 0, 0);
            acc11 = __builtin_amdgcn_mfma_f32_32x32x16_bf16(a1, bb, acc11, 0, 0, 0);
          }
        }
      }
    }
  } else {
    // ---- SLOW PATH (tile 63, wave 3 only — 32 of 8192 waves): scalar
    // clamped loads; dwordx4 here would read past the end of x.
#pragma unroll
    for (int s = 0; s < 12; ++s) {
      bf16x8 a0 = *(const bf16x8*)&wl[ln * PW + s * 16 + kh];
      bf16x8 a1 = *(const bf16x8*)&wl[(32 + ln) * PW + s * 16 + kh];
      int tt = s * 16 + kh;
      int kk = tt >> 6;           // uniform over the 8-elem fragment
      int ci0 = tt & 63;
      int p0 = min(l_a + kk, L_IN - 1);
      int p1 = min(l_a + 32 + kk, L_IN - 1);
      const float* base = xb + (size_t)ci0 * L_IN;
      bf16x8 b0, b1;
#pragma unroll
      for (int jj = 0; jj < 8; ++jj) {
        b0[jj] = (__bf16)base[(size_t)jj * L_IN + p0];
        b1[jj] = (__bf16)base[(size_t)jj * L_IN + p1];
      }
      acc00 = __builtin_amdgcn_mfma_f32_32x32x16_bf16(a0, b0, acc00, 0, 0, 0);
      acc01 = __builtin_amdgcn_mfma_f32_32x32x16_bf16(a0, b1, acc01, 0, 0, 0);
      acc10 = __builtin_amdgcn_mfma_f32_32x32x16_bf16(a1, b0, acc10, 0, 0, 0);
      acc11 = __builtin_amdgcn_mfma_f32_32x32x16_bf16(a1, b1, acc11, 0, 0, 0);
    }
  }

  // ---- epilogue: transpose through LDS, flush with coalesced dwordx4.
  // C/D layout: col = lane&31 -> n; row r -> co_local = (r&3)+8*(r>>2)+4*half.
  const bool full = (l0 + NT <= L_OUT);  // tiles 0..62
  __syncthreads();                        // everyone done reading wl

#pragma unroll
  for (int H = 0; H < 2; ++H) {
    // stage co-half H into buf[32][256]
#pragma unroll
    for (int r = 0; r < 16; ++r) {
      int col_ = (r & 3) + 8 * (r >> 2) + 4 * half;   // co_local 0..31
      float bv = bias_s[H * 32 + col_];
      float v0 = (H == 0 ? acc00[r] : acc10[r]) + bv;
      float v1 = (H == 0 ? acc01[r] : acc11[r]) + bv;
      buf[col_][wv * 64 + ln] = v0;
      buf[col_][wv * 64 + 32 + ln] = v1;
    }
    __syncthreads();
    // flush: 32 rows x 64 x4-chunks = 2048 chunks, 8 per thread.
    // consecutive threads -> consecutive chunks: 1024 B contiguous per row.
#pragma unroll
    for (int i = 0; i < 8; ++i) {
      int idx = t + i * 256;
      int row = idx >> 6;          // 0..31
      int ch = idx & 63;           // 0..63
      f32x4a v = *(const f32x4a*)&buf[row][ch * 4];
      size_t obase = ((size_t)(b * 64 + H * 32 + row)) * L_OUT + l0 + ch * 4;
      if (full || (l0 + ch * 4 + 3 < L_OUT)) {
        *(f32x4u*)(out + obase) = v;
      } else {
#pragma unroll
        for (int e = 0; e < 4; ++e)
          if (l0 + ch * 4 + e < L_OUT) out[obase + e] = v[e];
      }
    }
    __syncthreads();   // buf free for next half
  }
}

extern "C" void kernel_launch(void* const* d_in, const int* in_sizes, int n_in,
                              void* d_out, int out_size, void* d_ws, size_t ws_size,
                              hipStream_t stream) {
  const float* x = (const float*)d_in[0];
  const float* w = (const float*)d_in[1];
  const float* bias = (const float*)d_in[2];
  float* out = (float*)d_out;
  // 32 batches * 64 l-tiles of 256 columns
  conv1d_mfma<<<dim3(32 * 64), dim3(256), 0, stream>>>(x, w, bias, out);
}

// Round 3
// 286.927 us; speedup vs baseline: 1.4197x; 1.4197x over previous
//
#include <hip/hip_runtime.h>

// Conv1d: x (32, 64, 16384) f32, w (64, 64, 3) f32, bias (64) f32
// -> out (32, 64, 16382) f32, VALID, stride 1.
// GEMM view: out[co][n] = sum_kappa A[co][kappa] * B[kappa][n] + bias[co]
//   kappa = kk*64 + ci (kk-major). B[kappa][n] = x[ci][n+kk].
//
// R3 structure (vs R1/R2 which spilled ~380MB of scratch to HBM):
//  - x tile staged ONCE per block into LDS as bf16, TRANSPOSED: xt[col][ci].
//    A B-fragment (8 consecutive ci, fixed col) is then 16 contiguous bytes
//    -> ds_read_b128. Pitch 72 elems (144B = 9*16B): 16B-aligned b128 reads,
//    4-bank row stride -> ~4-way conflicts (free-ish), no XOR swizzle needed.
//  - wave-tile 64co x 32col: only 2 f32x16 accumulators (32 AGPR). Total
//    register demand ~90 << 128/wave cap -> no scratch spills by construction.
//  - 9 coalesced dwordx4 global loads per thread total (vs 64 per lane in R2).
//  - NT=128, LDS = 25600(wl) + 19008(xt) + 256(bias) = 44.9KB -> 3 blocks/CU.

typedef __bf16 bf16x8 __attribute__((ext_vector_type(8)));
typedef float f32x16 __attribute__((ext_vector_type(16)));
typedef float f32x4u __attribute__((ext_vector_type(4), aligned(4)));

#define C_IN 64
#define C_OUT 64
#define L_IN 16384
#define L_OUT 16382
#define NT 128          // n-columns per block
#define TILES 128       // L_IN / NT
#define PW 200          // wl row pitch (elems): 400B -> 4-bank stride, 16B mult
#define XT_P 72         // xt row pitch (elems): 144B = 9*16B -> aligned b128, 4-bank stride
#define XT_COLS (NT + 4)  // 128 cols + 3 halo + 1 pad

__global__ __launch_bounds__(256, 3) void conv1d_mfma(
    const float* __restrict__ x, const float* __restrict__ w,
    const float* __restrict__ bias, float* __restrict__ out) {
  __shared__ __align__(16) __bf16 wl[C_OUT * PW];       // 25600 B
  __shared__ __align__(16) __bf16 xt[XT_COLS * XT_P];   // 19008 B
  __shared__ float bias_s[C_OUT];

  const int t = threadIdx.x;
  const int bx = blockIdx.x;
  const int b = bx >> 7;         // batch
  const int tile = bx & 127;     // l-tile
  const int l0 = tile * NT;

  const float* xb = x + (size_t)b * (C_IN * L_IN);

  // ---- weights -> LDS bf16, layout wl[co][kk*64 + ci] (kappa kk-major)
  for (int i = t; i < C_OUT * 192; i += 256) {
    int co = i / 192;
    int r = i - co * 192;
    int ci = r / 3;
    int kk = r - ci * 3;
    wl[co * PW + kk * 64 + ci] = (__bf16)w[i];
  }
  if (t < C_OUT) bias_s[t] = bias[t];

  // ---- x tile -> LDS bf16 transposed: xt[col][ci] = x[ci][l0+col]
  // 64 ci x 33 dwordx4 chunks (132 cols incl 3-col halo + 1 spare).
  // Mapping: consecutive threads -> consecutive chunks of the SAME ci
  // (coalesced global reads, 33 lanes cover 528 contiguous bytes).
  for (int idx = t; idx < C_IN * 33; idx += 256) {
    int ci = idx / 33;
    int cc = idx - ci * 33;
    int gc = l0 + cc * 4;
    if (gc > L_IN - 4) gc = L_IN - 4;   // only tile 127, cc 32: feeds cols whose
                                        // outputs are never stored (values moot)
    f32x4u v = *(const f32x4u*)(xb + (size_t)ci * L_IN + gc);
    int col = cc * 4;
    xt[(col + 0) * XT_P + ci] = (__bf16)v[0];
    xt[(col + 1) * XT_P + ci] = (__bf16)v[1];
    xt[(col + 2) * XT_P + ci] = (__bf16)v[2];
    xt[(col + 3) * XT_P + ci] = (__bf16)v[3];
  }
  __syncthreads();

  // ---- MFMA loop: wave wv owns cols [wv*32, wv*32+32), all 64 co.
  const int lane = t & 63;
  const int wv = t >> 6;
  const int half = lane >> 5;   // k-half within fragment
  const int ln = lane & 31;
  const int kh = half * 8;

  f32x16 acc0 = {}, acc1 = {};  // co 0..31 / co 32..63

#pragma unroll
  for (int s = 0; s < 12; ++s) {
    int kap = s * 16 + kh;          // kappa of first fragment element
    int kk = kap >> 6;              // uniform over the 8-elem fragment
    int ci0 = kap & 63;
    int col = wv * 32 + ln + kk;    // <= 127 + 3 = 130 < XT_COLS
    bf16x8 bf = *(const bf16x8*)&xt[col * XT_P + ci0];
    bf16x8 a0 = *(const bf16x8*)&wl[ln * PW + kap];
    bf16x8 a1 = *(const bf16x8*)&wl[(32 + ln) * PW + kap];
    acc0 = __builtin_amdgcn_mfma_f32_32x32x16_bf16(a0, bf, acc0, 0, 0, 0);
    acc1 = __builtin_amdgcn_mfma_f32_32x32x16_bf16(a1, bf, acc1, 0, 0, 0);
  }

  // ---- epilogue: C/D layout col(lane&31) = n, row r -> co_local.
  // Per store inst: 32 lanes write 128B contiguous (two co rows per wave).
  const int nl = wv * 32 + ln;          // local n, 0..127
  const int ng = l0 + nl;               // global n
  if (tile != TILES - 1) {
#pragma unroll
    for (int h = 0; h < 2; ++h) {
#pragma unroll
      for (int r = 0; r < 16; ++r) {
        int co = h * 32 + 4 * half + (r & 3) + 8 * (r >> 2);
        float v = (h == 0 ? acc0[r] : acc1[r]) + bias_s[co];
        out[(size_t)(b * C_OUT + co) * L_OUT + ng] = v;
      }
    }
  } else {
#pragma unroll
    for (int h = 0; h < 2; ++h) {
#pragma unroll
      for (int r = 0; r < 16; ++r) {
        int co = h * 32 + 4 * half + (r & 3) + 8 * (r >> 2);
        float v = (h == 0 ? acc0[r] : acc1[r]) + bias_s[co];
        if (ng < L_OUT) out[(size_t)(b * C_OUT + co) * L_OUT + ng] = v;
      }
    }
  }
}

extern "C" void kernel_launch(void* const* d_in, const int* in_sizes, int n_in,
                              void* d_out, int out_size, void* d_ws, size_t ws_size,
                              hipStream_t stream) {
  const float* x = (const float*)d_in[0];
  const float* w = (const float*)d_in[1];
  const float* bias = (const float*)d_in[2];
  float* out = (float*)d_out;
  // 32 batches * 128 l-tiles of 128 columns
  conv1d_mfma<<<dim3(32 * 128), dim3(256), 0, stream>>>(x, w, bias, out);
}